// Round 1
// baseline (36557.581 us; speedup 1.0000x reference)
//
#include <hip/hip_runtime.h>
#include <cstddef>

#define B_ 64
#define L_ 256
#define E_ 512
#define H_ 512
#define N_ 128
#define D_ 64
#define R_ 4
#define O_ 2048
#define CI_ 768
#define TO_ 768

__device__ __forceinline__ float sigmoidf(float x){ return 1.0f/(1.0f+expf(-x)); }

// Block-wide sum of two values across exactly 4 waves (256 threads).
__device__ __forceinline__ void block_sum2(float& a, float& b, float* scr, int tid){
    #pragma unroll
    for (int o=32;o>0;o>>=1){ a += __shfl_down(a,o,64); b += __shfl_down(b,o,64); }
    __syncthreads();                       // protect scr from previous use
    if ((tid&63)==0){ scr[(tid>>6)*2]=a; scr[(tid>>6)*2+1]=b; }
    __syncthreads();
    a = scr[0]+scr[2]+scr[4]+scr[6];
    b = scr[1]+scr[3]+scr[5]+scr[7];
}

// K1: gates GEMV + LSTM cell update (waves 0-3), prev-step output projection (waves 4-7).
// grid 256 blocks x 512 threads. lane = batch. block owns h-cols {2*blk, 2*blk+1} and
// proj cols [8*blk, 8*blk+8).
__global__ __launch_bounds__(512,1) void k1_kernel(
    const float* __restrict__ ci, const float* __restrict__ hprev,
    float* __restrict__ hnew, float* __restrict__ cst,
    const float* __restrict__ po,
    const float* __restrict__ W_ih, const float* __restrict__ W_hh,
    const float* __restrict__ b_ih, const float* __restrict__ b_hh,
    const float* __restrict__ W_proj, const float* __restrict__ b_proj,
    float* __restrict__ out, int t)
{
    const int tid = threadIdx.x, w = tid>>6, lane = tid&63, blk = blockIdx.x;
    __shared__ float gsm[2][4][64];

    if (w < 4 && t < L_){
        const int q = w;                       // gate index (i,f,g,o)
        const int j0 = 2*blk, j1 = 2*blk+1;    // h columns
        const float* wa = W_ih + (size_t)(q*H_ + j0)*CI_;
        const float* wb = W_ih + (size_t)(q*H_ + j1)*CI_;
        const float* xr = ci + (size_t)lane*CI_;
        float a0=0,a1=0,a2=0,a3=0, c0=0,c1=0,c2=0,c3=0;
        #pragma unroll 4
        for (int k=0;k<CI_;k+=4){
            float4 x = *(const float4*)(xr+k);
            float4 u = *(const float4*)(wa+k);
            float4 v = *(const float4*)(wb+k);
            a0+=x.x*u.x; a1+=x.y*u.y; a2+=x.z*u.z; a3+=x.w*u.w;
            c0+=x.x*v.x; c1+=x.y*v.y; c2+=x.z*v.z; c3+=x.w*v.w;
        }
        const float* wa2 = W_hh + (size_t)(q*H_ + j0)*H_;
        const float* wb2 = W_hh + (size_t)(q*H_ + j1)*H_;
        const float* hr  = hprev + (size_t)lane*H_;
        #pragma unroll 4
        for (int k=0;k<H_;k+=4){
            float4 x = *(const float4*)(hr+k);
            float4 u = *(const float4*)(wa2+k);
            float4 v = *(const float4*)(wb2+k);
            a0+=x.x*u.x; a1+=x.y*u.y; a2+=x.z*u.z; a3+=x.w*u.w;
            c0+=x.x*v.x; c1+=x.y*v.y; c2+=x.z*v.z; c3+=x.w*v.w;
        }
        gsm[0][q][lane] = a0+a1+a2+a3 + b_ih[q*H_+j0] + b_hh[q*H_+j0];
        gsm[1][q][lane] = c0+c1+c2+c3 + b_ih[q*H_+j1] + b_hh[q*H_+j1];
    }
    __syncthreads();
    if (w < 2 && t < L_){
        const int j = 2*blk + w;
        float gi=gsm[w][0][lane], gf=gsm[w][1][lane], gg=gsm[w][2][lane], go=gsm[w][3][lane];
        const int idx = lane*H_ + j;
        float cn = sigmoidf(gf)*cst[idx] + sigmoidf(gi)*tanhf(gg);
        cst[idx]  = cn;
        hnew[idx] = sigmoidf(go)*tanhf(cn);
    }
    if (w >= 4 && t > 0){
        const int p0 = 8*blk + 2*(w-4);
        const float* wa = W_proj + (size_t)p0*TO_;
        const float* wb = W_proj + (size_t)(p0+1)*TO_;
        const float* xr = po + (size_t)lane*TO_;
        float a0=0,a1=0,a2=0,a3=0, c0=0,c1=0,c2=0,c3=0;
        #pragma unroll 4
        for (int k=0;k<TO_;k+=4){
            float4 x = *(const float4*)(xr+k);
            float4 u = *(const float4*)(wa+k);
            float4 v = *(const float4*)(wb+k);
            a0+=x.x*u.x; a1+=x.y*u.y; a2+=x.z*u.z; a3+=x.w*u.w;
            c0+=x.x*v.x; c1+=x.y*v.y; c2+=x.z*v.z; c3+=x.w*v.w;
        }
        const size_t ob = ((size_t)lane*L_ + (t-1))*O_;
        out[ob + p0]     = a0+a1+a2+a3 + b_proj[p0];
        out[ob + p0 + 1] = c0+c1+c2+c3 + b_proj[p0+1];
    }
}

// K2: per-batch block. LN(h)->hn, head GEMVs, write softmax+mem update,
// read softmax+rv, po = LN(hn||rv), ci_{t+1} = LN(x_{t+1}||rv).
__global__ __launch_bounds__(256,1) void k2_kernel(
    const float* __restrict__ h,
    float* __restrict__ mem,
    float* __restrict__ rv,
    float* __restrict__ ci,
    float* __restrict__ po,
    const float* __restrict__ x_emb,
    const float* __restrict__ g_ctrl, const float* __restrict__ b_ctrl,
    const float* __restrict__ W_rk, const float* __restrict__ b_rk,
    const float* __restrict__ W_wk, const float* __restrict__ b_wk,
    const float* __restrict__ W_ws, const float* __restrict__ b_ws,
    const float* __restrict__ W_er, const float* __restrict__ b_er,
    const float* __restrict__ W_ad, const float* __restrict__ b_ad,
    const float* __restrict__ g_rk, const float* __restrict__ b_ln_rk,
    const float* __restrict__ g_wk, const float* __restrict__ b_ln_wk,
    const float* __restrict__ g_mem, const float* __restrict__ b_ln_mem,
    const float* __restrict__ g_in, const float* __restrict__ b_in,
    const float* __restrict__ g_out, const float* __restrict__ b_out,
    int t)
{
    const int b = blockIdx.x, tid = threadIdx.x;
    __shared__ __align__(16) float hn[H_];
    __shared__ float rks[R_][D_];
    __shared__ float wks[D_];
    __shared__ float ers[D_], ads[D_];
    __shared__ float sc[N_];
    __shared__ float s2[R_][N_];
    __shared__ float mstat[2][N_];
    __shared__ float rvs[R_*D_];
    __shared__ float scr[8];
    __shared__ float wss_s;

    // ---- A: hn = LN(h) ----
    const float* hb = h + (size_t)b*H_;
    float v0 = hb[tid], v1 = hb[tid+256];
    float s = v0+v1, q = v0*v0+v1*v1;
    block_sum2(s,q,scr,tid);
    {
        float m  = s*(1.f/H_);
        float rs = rsqrtf(q*(1.f/H_) - m*m + 1e-5f);
        hn[tid]     = (v0-m)*rs*g_ctrl[tid]     + b_ctrl[tid];
        hn[tid+256] = (v1-m)*rs*g_ctrl[tid+256] + b_ctrl[tid+256];
    }
    __syncthreads();

    // ---- B: head GEMVs (2 outputs/thread) ----
    {
        const float* wr = W_rk + (size_t)tid*H_;
        float a0=0,a1=0,a2=0,a3=0;
        for (int k=0;k<H_;k+=4){
            float4 u = *(const float4*)(wr+k);
            float4 x = *(const float4*)(hn+k);
            a0+=u.x*x.x; a1+=u.y*x.y; a2+=u.z*x.z; a3+=u.w*x.w;
        }
        rks[tid>>6][tid&63] = a0+a1+a2+a3 + b_rk[tid];
    }
    {
        const float* wr2 = nullptr; float bias2 = 0.f;
        if (tid < 64)        { wr2 = W_wk + (size_t)tid*H_;       bias2 = b_wk[tid]; }
        else if (tid < 128)  { wr2 = W_er + (size_t)(tid-64)*H_;  bias2 = b_er[tid-64]; }
        else if (tid < 192)  { wr2 = W_ad + (size_t)(tid-128)*H_; bias2 = b_ad[tid-128]; }
        else if (tid == 192) { wr2 = W_ws;                        bias2 = b_ws[0]; }
        if (wr2){
            float a0=0,a1=0,a2=0,a3=0;
            for (int k=0;k<H_;k+=4){
                float4 u = *(const float4*)(wr2+k);
                float4 x = *(const float4*)(hn+k);
                a0+=u.x*x.x; a1+=u.y*x.y; a2+=u.z*x.z; a3+=u.w*x.w;
            }
            float a = a0+a1+a2+a3 + bias2;
            if (tid < 64)       wks[tid] = a;
            else if (tid < 128) ers[tid-64]  = sigmoidf(a);
            else if (tid < 192) ads[tid-128] = tanhf(a);
            else                wss_s = sigmoidf(a);
        }
    }
    __syncthreads();

    // ---- rkn (wave r owns row r), then wkn (wave 0) ----
    {
        int r = tid>>6, d = tid&63;
        float v = rks[r][d];
        float ss=v, qq=v*v;
        #pragma unroll
        for (int o=32;o>0;o>>=1){ ss+=__shfl_down(ss,o,64); qq+=__shfl_down(qq,o,64); }
        ss=__shfl(ss,0,64); qq=__shfl(qq,0,64);
        float mr = ss*(1.f/D_);
        float rr = rsqrtf(qq*(1.f/D_)-mr*mr+1e-5f);
        rks[r][d] = (v-mr)*rr*g_rk[d]+b_ln_rk[d];
    }
    if (tid < 64){
        float v = wks[tid];
        float ss=v, qq=v*v;
        #pragma unroll
        for (int o=32;o>0;o>>=1){ ss+=__shfl_down(ss,o,64); qq+=__shfl_down(qq,o,64); }
        ss=__shfl(ss,0,64); qq=__shfl(qq,0,64);
        float mr = ss*(1.f/D_);
        float rr = rsqrtf(qq*(1.f/D_)-mr*mr+1e-5f);
        wks[tid] = (v-mr)*rr*g_wk[tid]+b_ln_wk[tid];
    }
    __syncthreads();

    // ---- C: write scores (pre-write LN(mem)) + softmax*ws ----
    float* mrow0 = mem + (size_t)b*N_*D_;
    if (tid < N_){
        const float* row = mrow0 + tid*D_;
        float ss=0,qq=0;
        for (int d=0;d<D_;d+=4){
            float4 u = *(const float4*)(row+d);
            ss += u.x+u.y+u.z+u.w;
            qq += u.x*u.x+u.y*u.y+u.z*u.z+u.w*u.w;
        }
        float mr = ss*(1.f/D_);
        float rr = rsqrtf(qq*(1.f/D_)-mr*mr+1e-5f);
        float acc = 0.f;
        for (int d=0;d<D_;d++)
            acc += wks[d]*((row[d]-mr)*rr*g_mem[d]+b_ln_mem[d]);
        sc[tid] = acc;
    }
    __syncthreads();
    if (tid < 64){
        float v = fmaxf(sc[tid], sc[tid+64]);
        #pragma unroll
        for (int o=32;o>0;o>>=1) v = fmaxf(v, __shfl_down(v,o,64));
        v = __shfl(v,0,64);
        float e0 = expf(sc[tid]-v), e1 = expf(sc[tid+64]-v);
        float se = e0+e1;
        #pragma unroll
        for (int o=32;o>0;o>>=1) se += __shfl_down(se,o,64);
        se = __shfl(se,0,64);
        float inv = wss_s/se;
        sc[tid]    = e0*inv;
        sc[tid+64] = e1*inv;
    }
    __syncthreads();

    // ---- D: memory update (in-place, block-private) ----
    for (int i = tid; i < N_*D_; i += 256){
        int n = i>>6, d = i&63;
        float ww = sc[n];
        mrow0[i] = mrow0[i]*(1.f - ww*ers[d]) + ww*ads[d];
    }
    __syncthreads();

    // ---- E: post-write row stats, read scores, per-r softmax ----
    if (tid < N_){
        const float* row = mrow0 + tid*D_;
        float ss=0,qq=0;
        for (int d=0;d<D_;d+=4){
            float4 u = *(const float4*)(row+d);
            ss += u.x+u.y+u.z+u.w;
            qq += u.x*u.x+u.y*u.y+u.z*u.z+u.w*u.w;
        }
        float mr = ss*(1.f/D_);
        mstat[0][tid] = mr;
        mstat[1][tid] = rsqrtf(qq*(1.f/D_)-mr*mr+1e-5f);
    }
    __syncthreads();
    {
        int r0 = tid>>7, n = tid&127;   // this thread does r0 and r0+2
        const float* row = mrow0 + n*D_;
        float mr = mstat[0][n], rr = mstat[1][n];
        float a0=0,a1=0;
        for (int d=0;d<D_;d++){
            float nm = (row[d]-mr)*rr*g_mem[d]+b_ln_mem[d];
            a0 += rks[r0][d]*nm;
            a1 += rks[r0+2][d]*nm;
        }
        s2[r0][n]=a0; s2[r0+2][n]=a1;
    }
    __syncthreads();
    {
        int r = tid>>6, lane = tid&63;
        float v = fmaxf(s2[r][lane], s2[r][lane+64]);
        #pragma unroll
        for (int o=32;o>0;o>>=1) v = fmaxf(v, __shfl_down(v,o,64));
        v = __shfl(v,0,64);
        float e0 = expf(s2[r][lane]-v), e1 = expf(s2[r][lane+64]-v);
        float se = e0+e1;
        #pragma unroll
        for (int o=32;o>0;o>>=1) se += __shfl_down(se,o,64);
        se = __shfl(se,0,64);
        float inv = 1.f/se;
        s2[r][lane]    = e0*inv;
        s2[r][lane+64] = e1*inv;
    }
    __syncthreads();

    // ---- F: rvec = rw @ mem ----
    {
        int r = tid>>6, d = tid&63;
        float acc=0;
        for (int n=0;n<N_;n++) acc += s2[r][n]*mrow0[n*D_+d];
        rvs[tid] = acc;
        rv[(size_t)b*R_*D_ + tid] = acc;
    }
    __syncthreads();

    // ---- G: po = LN(hn || rv) ----
    {
        float u0=hn[tid], u1=hn[tid+256], u2=rvs[tid];
        float ssum=u0+u1+u2, sq=u0*u0+u1*u1+u2*u2;
        block_sum2(ssum,sq,scr,tid);
        float mo = ssum*(1.f/TO_);
        float ro = rsqrtf(sq*(1.f/TO_)-mo*mo+1e-5f);
        float* pb = po + (size_t)b*TO_;
        pb[tid]     = (u0-mo)*ro*g_out[tid]    +b_out[tid];
        pb[tid+256] = (u1-mo)*ro*g_out[tid+256]+b_out[tid+256];
        pb[tid+512] = (u2-mo)*ro*g_out[tid+512]+b_out[tid+512];
    }
    // ---- H: ci_{t+1} = LN(x_{t+1} || rv) ----
    if (t < L_-1){
        const float* xr = x_emb + ((size_t)b*L_ + t + 1)*E_;
        float u0=xr[tid], u1=xr[tid+256], u2=rvs[tid];
        float ssum=u0+u1+u2, sq=u0*u0+u1*u1+u2*u2;
        block_sum2(ssum,sq,scr,tid);
        float mo = ssum*(1.f/CI_);
        float ro = rsqrtf(sq*(1.f/CI_)-mo*mo+1e-5f);
        float* cb = ci + (size_t)b*CI_;
        cb[tid]     = (u0-mo)*ro*g_in[tid]    +b_in[tid];
        cb[tid+256] = (u1-mo)*ro*g_in[tid+256]+b_in[tid+256];
        cb[tid+512] = (u2-mo)*ro*g_in[tid+512]+b_in[tid+512];
    }
}

// ci_0 = LN(x_0 || 0)   (rv buffer is pre-zeroed)
__global__ __launch_bounds__(256,1) void ci0_kernel(
    const float* __restrict__ x_emb, const float* __restrict__ rv,
    const float* __restrict__ g_in, const float* __restrict__ b_in,
    float* __restrict__ ci)
{
    int b = blockIdx.x, tid = threadIdx.x;
    __shared__ float scr[8];
    const float* xr = x_emb + (size_t)b*L_*E_;   // t = 0
    float u0=xr[tid], u1=xr[tid+256], u2=rv[(size_t)b*R_*D_+tid];
    float s=u0+u1+u2, q=u0*u0+u1*u1+u2*u2;
    block_sum2(s,q,scr,tid);
    float m  = s*(1.f/CI_);
    float rs = rsqrtf(q*(1.f/CI_)-m*m+1e-5f);
    float* cb = ci + (size_t)b*CI_;
    cb[tid]     = (u0-m)*rs*g_in[tid]    +b_in[tid];
    cb[tid+256] = (u1-m)*rs*g_in[tid+256]+b_in[tid+256];
    cb[tid+512] = (u2-m)*rs*g_in[tid+512]+b_in[tid+512];
}

__global__ void epi_kernel(const float* __restrict__ mem, const float* __restrict__ hfin,
                           const float* __restrict__ cfin, float* __restrict__ out)
{
    size_t i = (size_t)blockIdx.x*256 + threadIdx.x;
    const size_t o0 = (size_t)B_*L_*O_;
    if (i < (size_t)B_*N_*D_) out[o0 + i] = mem[i];
    if (i < (size_t)B_*H_){
        out[o0 + (size_t)B_*N_*D_ + i]              = hfin[i];
        out[o0 + (size_t)B_*N_*D_ + (size_t)B_*H_ + i] = cfin[i];
    }
}

extern "C" void kernel_launch(void* const* d_in, const int* in_sizes, int n_in,
                              void* d_out, int out_size, void* d_ws, size_t ws_size,
                              hipStream_t stream)
{
    const float* x_emb  = (const float*)d_in[0];
    const float* g_in   = (const float*)d_in[1];
    const float* b_in   = (const float*)d_in[2];
    const float* W_ih   = (const float*)d_in[3];
    const float* W_hh   = (const float*)d_in[4];
    const float* b_ih   = (const float*)d_in[5];
    const float* b_hh   = (const float*)d_in[6];
    const float* g_ctrl = (const float*)d_in[7];
    const float* b_ctrl = (const float*)d_in[8];
    const float* W_rk   = (const float*)d_in[9];
    const float* b_rk   = (const float*)d_in[10];
    const float* W_wk   = (const float*)d_in[11];
    const float* b_wk   = (const float*)d_in[12];
    const float* W_ws   = (const float*)d_in[13];
    const float* b_ws   = (const float*)d_in[14];
    const float* W_er   = (const float*)d_in[15];
    const float* b_er   = (const float*)d_in[16];
    const float* W_ad   = (const float*)d_in[17];
    const float* b_ad   = (const float*)d_in[18];
    const float* g_rk   = (const float*)d_in[19];
    const float* b_ln_rk= (const float*)d_in[20];
    const float* g_wk   = (const float*)d_in[21];
    const float* b_ln_wk= (const float*)d_in[22];
    const float* g_mem  = (const float*)d_in[23];
    const float* b_ln_mem=(const float*)d_in[24];
    const float* g_out  = (const float*)d_in[25];
    const float* b_out  = (const float*)d_in[26];
    const float* W_proj = (const float*)d_in[27];
    const float* b_proj = (const float*)d_in[28];

    float* ws  = (float*)d_ws;
    // ws layout (floats). Zeroed region is contiguous [0, 606208).
    float* hb0 = ws + 0;        // [64][512]
    float* cst = ws + 32768;    // [64][512]
    float* mem = ws + 65536;    // [64][128][64]
    float* rv  = ws + 589824;   // [64][256]
    float* hb1 = ws + 606208;   // [64][512]   (written before read)
    float* ci  = ws + 638976;   // [64][768]
    float* po  = ws + 688128;   // [64][768]
    float* out = (float*)d_out;

    hipMemsetAsync(ws, 0, 606208*sizeof(float), stream);
    ci0_kernel<<<64,256,0,stream>>>(x_emb, rv, g_in, b_in, ci);

    for (int t=0; t<=L_; ++t){
        float* hprev = (t&1)? hb1 : hb0;
        float* hnew  = (t&1)? hb0 : hb1;
        k1_kernel<<<256,512,0,stream>>>(ci, hprev, hnew, cst, po,
            W_ih, W_hh, b_ih, b_hh, W_proj, b_proj, out, t);
        if (t < L_)
            k2_kernel<<<64,256,0,stream>>>(hnew, mem, rv, ci, po, x_emb,
                g_ctrl,b_ctrl, W_rk,b_rk, W_wk,b_wk, W_ws,b_ws, W_er,b_er, W_ad,b_ad,
                g_rk,b_ln_rk, g_wk,b_ln_wk, g_mem,b_ln_mem, g_in,b_in, g_out,b_out, t);
    }
    // final h lives in hb0 (t=255 is odd -> wrote hb0)
    epi_kernel<<<2048,256,0,stream>>>(mem, hb0, cst, out);
}

// Round 3
// 24248.495 us; speedup vs baseline: 1.5076x; 1.5076x over previous
//
#include <hip/hip_runtime.h>
#include <cstddef>

#define B_ 64
#define L_ 256
#define E_ 512
#define H_ 512
#define N_ 128
#define D_ 64
#define R_ 4
#define O_ 2048
#define CI_ 768
#define TO_ 768
#define KG_ 1280   // gates GEMM K = CI + H
#define KP_ 768    // proj GEMM K = TO

typedef short v8s __attribute__((ext_vector_type(8)));
typedef float v4f __attribute__((ext_vector_type(4)));

__device__ __forceinline__ float sigmoidf(float x){ return 1.0f/(1.0f+expf(-x)); }

__device__ __forceinline__ unsigned short f2bf(float f){
    unsigned int u = __float_as_uint(f);
    u = (u + 0x7FFFu + ((u >> 16) & 1u)) >> 16;
    return (unsigned short)u;
}

// Block-wide sum of two values across exactly 4 waves (256 threads).
__device__ __forceinline__ void block_sum2(float& a, float& b, float* scr, int tid){
    #pragma unroll
    for (int o=32;o>0;o>>=1){ a += __shfl_down(a,o,64); b += __shfl_down(b,o,64); }
    __syncthreads();
    if ((tid&63)==0){ scr[(tid>>6)*2]=a; scr[(tid>>6)*2+1]=b; }
    __syncthreads();
    a = scr[0]+scr[2]+scr[4]+scr[6];
    b = scr[1]+scr[3]+scr[5]+scr[7];
}

// ---------- one-time weight conversion ----------
// W_g_bf[c][k], c = j*4+q (unit-major, gate-minor), k in [0,1280): [W_ih | W_hh] rows.
__global__ void convG_kernel(const float* __restrict__ W_ih, const float* __restrict__ W_hh,
                             const float* __restrict__ b_ih, const float* __restrict__ b_hh,
                             unsigned short* __restrict__ Wg, float* __restrict__ biasg)
{
    int bid = blockIdx.x;            // 2048*5 blocks
    int c = bid/5, kc = bid%5;
    int k = kc*256 + threadIdx.x;
    int j = c>>2, q = c&3;
    int row = q*H_ + j;
    float v = (k < CI_) ? W_ih[(size_t)row*CI_ + k] : W_hh[(size_t)row*H_ + (k-CI_)];
    Wg[(size_t)c*KG_ + k] = f2bf(v);
    if (kc==0 && threadIdx.x==0) biasg[c] = b_ih[row] + b_hh[row];
}

__global__ void convP_kernel(const float* __restrict__ W_proj, unsigned short* __restrict__ Wp)
{
    int bid = blockIdx.x;            // 2048*3 blocks
    int c = bid/3, kc = bid%3;
    int k = kc*256 + threadIdx.x;
    Wp[(size_t)c*KP_ + k] = f2bf(W_proj[(size_t)c*KP_ + k]);
}

// ---------- K1: MFMA gates GEMM + cell update (blocks 0..15), proj GEMM (blocks 16..31) ----------
__global__ __launch_bounds__(256,1) void k1_mfma(
    const unsigned short* __restrict__ Wg, const unsigned short* __restrict__ Wp,
    const float* __restrict__ biasg, const float* __restrict__ bproj,
    const unsigned short* __restrict__ act_cur, unsigned short* __restrict__ act_nxt,
    const unsigned short* __restrict__ po_bf,
    float* __restrict__ cst, float* __restrict__ h_nat, float* __restrict__ hsum,
    float* __restrict__ out, int t)
{
    const int tid = threadIdx.x, w = tid>>6, l = tid&63, bid = blockIdx.x;
    const int rl = l & 15, kg = l >> 4;
    __shared__ float gbuf[128][65];
    __shared__ float ps1[4][64], ps2[4][64];

    if (bid < 16){
        if (t >= L_) return;
        const int c0 = bid*128;
        v4f acc[8];
        #pragma unroll
        for (int mt=0; mt<8; ++mt) acc[mt] = (v4f){0.f,0.f,0.f,0.f};
        const unsigned short* aW = Wg + (size_t)(c0 + rl)*KG_ + kg*8;
        const unsigned short* bA = act_cur + (size_t)(w*16 + rl)*KG_ + kg*8;
        #pragma unroll 2
        for (int ks=0; ks<KG_/32; ++ks){
            v8s bfr = *(const v8s*)(bA + ks*32);
            #pragma unroll
            for (int mt=0; mt<8; ++mt){
                v8s afr = *(const v8s*)(aW + (size_t)mt*16*KG_ + ks*32);
                acc[mt] = __builtin_amdgcn_mfma_f32_16x16x32_bf16(afr, bfr, acc[mt], 0,0,0);
            }
        }
        #pragma unroll
        for (int mt=0; mt<8; ++mt)
            #pragma unroll
            for (int r=0; r<4; ++r)
                gbuf[mt*16 + kg*4 + r][w*16 + rl] = acc[mt][r];
        __syncthreads();
        float s1 = 0.f, s2 = 0.f;
        const int b = tid & 63;
        #pragma unroll
        for (int i=0; i<8; ++i){
            int u = (tid>>6) + i*4;
            float gi = gbuf[u*4+0][b] + biasg[c0+u*4+0];
            float gf = gbuf[u*4+1][b] + biasg[c0+u*4+1];
            float gg = gbuf[u*4+2][b] + biasg[c0+u*4+2];
            float go = gbuf[u*4+3][b] + biasg[c0+u*4+3];
            int j = bid*32 + u;
            size_t ix = (size_t)b*H_ + j;
            float cn = sigmoidf(gf)*cst[ix] + sigmoidf(gi)*tanhf(gg);
            cst[ix] = cn;
            float hv = sigmoidf(go)*tanhf(cn);
            h_nat[ix] = hv;
            act_nxt[(size_t)b*KG_ + CI_ + j] = f2bf(hv);
            s1 += hv; s2 += hv*hv;
        }
        ps1[w][b] = s1; ps2[w][b] = s2;
        __syncthreads();
        if (tid < 64){
            float a = ps1[0][tid]+ps1[1][tid]+ps1[2][tid]+ps1[3][tid];
            float d2 = ps2[0][tid]+ps2[1][tid]+ps2[2][tid]+ps2[3][tid];
            atomicAdd(&hsum[tid], a);
            atomicAdd(&hsum[64+tid], d2);
        }
    } else {
        if (t == 0) return;
        const int c0 = (bid-16)*128;
        v4f acc[8];
        #pragma unroll
        for (int mt=0; mt<8; ++mt) acc[mt] = (v4f){0.f,0.f,0.f,0.f};
        const unsigned short* aW = Wp + (size_t)(c0 + rl)*KP_ + kg*8;
        const unsigned short* bA = po_bf + (size_t)(w*16 + rl)*KP_ + kg*8;
        #pragma unroll 2
        for (int ks=0; ks<KP_/32; ++ks){
            v8s bfr = *(const v8s*)(bA + ks*32);
            #pragma unroll
            for (int mt=0; mt<8; ++mt){
                v8s afr = *(const v8s*)(aW + (size_t)mt*16*KP_ + ks*32);
                acc[mt] = __builtin_amdgcn_mfma_f32_16x16x32_bf16(afr, bfr, acc[mt], 0,0,0);
            }
        }
        #pragma unroll
        for (int mt=0; mt<8; ++mt)
            #pragma unroll
            for (int r=0; r<4; ++r)
                gbuf[mt*16 + kg*4 + r][w*16 + rl] = acc[mt][r];
        __syncthreads();
        // 128 cols x 64 batches = 2048 float4 stores; 256 threads -> 8 each
        #pragma unroll
        for (int p=0; p<8; ++p){
            int idx = tid + p*256;
            int c4 = idx & 31, b = idx >> 5;
            float4 v;
            v.x = gbuf[c4*4+0][b] + bproj[c0+c4*4+0];
            v.y = gbuf[c4*4+1][b] + bproj[c0+c4*4+1];
            v.z = gbuf[c4*4+2][b] + bproj[c0+c4*4+2];
            v.w = gbuf[c4*4+3][b] + bproj[c0+c4*4+3];
            *(float4*)(out + ((size_t)b*L_ + (t-1))*O_ + c0 + c4*4) = v;
        }
    }
}

// ---------- K2h: head GEMM, col-parallel, LN folded (rs*(S1 - m*C1) + C2) ----------
// grid 57 blocks x 256 thr; block covers global cols [bid*8, bid*8+8) of 449.
__global__ __launch_bounds__(256,1) void k2h_kernel(
    const float* __restrict__ h_nat, const float* __restrict__ hsum,
    const float* __restrict__ W_rk, const float* __restrict__ b_rk,
    const float* __restrict__ W_wk, const float* __restrict__ b_wk,
    const float* __restrict__ W_ws, const float* __restrict__ b_ws,
    const float* __restrict__ W_er, const float* __restrict__ b_er,
    const float* __restrict__ W_ad, const float* __restrict__ b_ad,
    const float* __restrict__ g_ctrl, const float* __restrict__ b_ctrl,
    float* __restrict__ headT)
{
    const int tid = threadIdx.x, w = tid>>6, l = tid&63, bid = blockIdx.x;
    __shared__ float xs[64][132];
    __shared__ float sp[4][8][64];
    __shared__ float c12[2][8];

    // resolve weight rows for this block's 8 cols
    const float* wp[8]; float bias[8];
    #pragma unroll
    for (int c=0; c<8; ++c){
        int cg = bid*8 + c;
        if      (cg < 256){ wp[c] = W_rk + (size_t)cg*H_;        bias[c] = b_rk[cg]; }
        else if (cg < 320){ wp[c] = W_wk + (size_t)(cg-256)*H_;  bias[c] = b_wk[cg-256]; }
        else if (cg < 384){ wp[c] = W_er + (size_t)(cg-320)*H_;  bias[c] = b_er[cg-320]; }
        else if (cg < 448){ wp[c] = W_ad + (size_t)(cg-384)*H_;  bias[c] = b_ad[cg-384]; }
        else              { wp[c] = W_ws;                        bias[c] = b_ws[0]; }
    }
    // C1[c] = sum_k w*g_ctrl ; C2[c] = sum_k w*b_ctrl + bias (lane l covers k = l*8..l*8+7)
    float c1r[8], c2r[8];
    #pragma unroll
    for (int c=0; c<8; ++c){
        float a1=0.f, a2=0.f;
        #pragma unroll
        for (int e=0; e<2; ++e){
            float4 wv = *(const float4*)(wp[c] + l*8 + e*4);
            float4 gv = *(const float4*)(g_ctrl + l*8 + e*4);
            float4 bv = *(const float4*)(b_ctrl + l*8 + e*4);
            a1 += wv.x*gv.x + wv.y*gv.y + wv.z*gv.z + wv.w*gv.w;
            a2 += wv.x*bv.x + wv.y*bv.y + wv.z*bv.z + wv.w*bv.w;
        }
        #pragma unroll
        for (int o=1; o<64; o<<=1){ a1 += __shfl_xor(a1,o,64); a2 += __shfl_xor(a2,o,64); }
        c1r[c]=a1; c2r[c]=a2+bias[c];
    }
    if (tid < 8){ c12[0][tid]=c1r[tid]; c12[1][tid]=c2r[tid]; }

    // S1[c][b] = sum_k w[c][k]*h[b][k], k chunked by 128, waves split k within chunk
    float acc[8];
    #pragma unroll
    for (int c=0; c<8; ++c) acc[c]=0.f;
    for (int ch=0; ch<4; ++ch){
        __syncthreads();
        #pragma unroll
        for (int p=0; p<8; ++p){
            int idx = tid + p*256;
            int f4 = idx & 31, b = idx >> 5;
            float4 v = *(const float4*)(h_nat + (size_t)b*H_ + ch*128 + f4*4);
            *(float4*)&xs[b][f4*4] = v;
        }
        __syncthreads();
        #pragma unroll
        for (int g=0; g<8; ++g){
            int kk = w*32 + g*4;                  // within-chunk k
            float4 xv = *(const float4*)&xs[l][kk];
            int k = ch*128 + kk;                  // global k
            #pragma unroll
            for (int c=0; c<8; ++c){
                float4 wv = *(const float4*)(wp[c] + k);
                acc[c] += xv.x*wv.x + xv.y*wv.y + xv.z*wv.z + xv.w*wv.w;
            }
        }
    }
    #pragma unroll
    for (int c=0; c<8; ++c) sp[w][c][l] = acc[c];
    __syncthreads();

    #pragma unroll
    for (int i=0; i<2; ++i){
        int idx = tid + i*256;
        int c = idx >> 6, b = idx & 63;
        float s = sp[0][c][b]+sp[1][c][b]+sp[2][c][b]+sp[3][c][b];
        float hs1 = hsum[b], hs2 = hsum[64+b];
        float mb = hs1*(1.f/H_);
        float rsb = rsqrtf(hs2*(1.f/H_) - mb*mb + 1e-5f);
        float val = rsb*(s - mb*c12[0][c]) + c12[1][c];
        int cg = bid*8 + c;
        if (cg < 449){
            if (cg >= 448)      val = sigmoidf(val);   // ws
            else if (cg >= 384) val = tanhf(val);      // ad
            else if (cg >= 320) val = sigmoidf(val);   // er
            headT[(size_t)cg*64 + b] = val;
        }
    }
}

// ---------- K2m: per-batch memory pipeline ----------
__global__ __launch_bounds__(256,1) void k2m_kernel(
    const float* __restrict__ h_nat, float* __restrict__ hsum,
    const float* __restrict__ headT, float* __restrict__ mem,
    unsigned short* __restrict__ act_nxt, unsigned short* __restrict__ po_bf,
    const float* __restrict__ x_emb,
    const float* __restrict__ g_ctrl, const float* __restrict__ b_ctrl,
    const float* __restrict__ g_rk, const float* __restrict__ b_ln_rk,
    const float* __restrict__ g_wk, const float* __restrict__ b_ln_wk,
    const float* __restrict__ g_mem, const float* __restrict__ b_ln_mem,
    const float* __restrict__ g_in, const float* __restrict__ b_in,
    const float* __restrict__ g_out, const float* __restrict__ b_out,
    int t)
{
    const int b = blockIdx.x, tid = threadIdx.x;
    __shared__ float hn_s[H_];
    __shared__ float rks[R_][D_];
    __shared__ float wks[D_];
    __shared__ float ers[D_], ads[D_];
    __shared__ float sc[N_];
    __shared__ float s2s[R_][N_];
    __shared__ float mst[2][N_];
    __shared__ float rvs[R_*D_];
    __shared__ float scr[8];
    __shared__ float wss_s;

    // per-batch LN stats from K1's atomic sums
    const float hs1 = hsum[b], hs2 = hsum[64+b];
    const float m = hs1*(1.f/H_);
    const float rs = rsqrtf(hs2*(1.f/H_) - m*m + 1e-5f);

    // A: hn
    {
        float v0 = h_nat[(size_t)b*H_ + tid], v1 = h_nat[(size_t)b*H_ + tid + 256];
        hn_s[tid]     = (v0-m)*rs*g_ctrl[tid]     + b_ctrl[tid];
        hn_s[tid+256] = (v1-m)*rs*g_ctrl[tid+256] + b_ctrl[tid+256];
    }
    // B: load heads, LN rk & wk
    {
        float v = headT[(size_t)tid*64 + b];   // rk raw, col = tid
        float ss=v, qq=v*v;
        #pragma unroll
        for (int o=32;o>0;o>>=1){ ss+=__shfl_down(ss,o,64); qq+=__shfl_down(qq,o,64); }
        ss=__shfl(ss,0,64); qq=__shfl(qq,0,64);
        float mr = ss*(1.f/D_);
        float rr = rsqrtf(qq*(1.f/D_)-mr*mr+1e-5f);
        int r = tid>>6, d = tid&63;
        rks[r][d] = (v-mr)*rr*g_rk[d]+b_ln_rk[d];
    }
    if (tid < 64){
        float v = headT[(size_t)(256+tid)*64 + b];
        float ss=v, qq=v*v;
        #pragma unroll
        for (int o=32;o>0;o>>=1){ ss+=__shfl_down(ss,o,64); qq+=__shfl_down(qq,o,64); }
        ss=__shfl(ss,0,64); qq=__shfl(qq,0,64);
        float mr = ss*(1.f/D_);
        float rr = rsqrtf(qq*(1.f/D_)-mr*mr+1e-5f);
        wks[tid] = (v-mr)*rr*g_wk[tid]+b_ln_wk[tid];
        ers[tid] = headT[(size_t)(320+tid)*64 + b];
        ads[tid] = headT[(size_t)(384+tid)*64 + b];
    }
    if (tid == 0) wss_s = headT[(size_t)448*64 + b];
    __syncthreads();

    // C: write scores (pre-write LN(mem))
    float* mrow0 = mem + (size_t)b*N_*D_;
    if (tid < N_){
        const float* row = mrow0 + tid*D_;
        float ss=0,qq=0;
        for (int d=0;d<D_;d+=4){
            float4 u = *(const float4*)(row+d);
            ss += u.x+u.y+u.z+u.w;
            qq += u.x*u.x+u.y*u.y+u.z*u.z+u.w*u.w;
        }
        float mr = ss*(1.f/D_);
        float rr = rsqrtf(qq*(1.f/D_)-mr*mr+1e-5f);
        float acc = 0.f;
        for (int d=0;d<D_;d++)
            acc += wks[d]*((row[d]-mr)*rr*g_mem[d]+b_ln_mem[d]);
        sc[tid] = acc;
    }
    __syncthreads();
    if (tid < 64){
        float v = fmaxf(sc[tid], sc[tid+64]);
        #pragma unroll
        for (int o=32;o>0;o>>=1) v = fmaxf(v, __shfl_down(v,o,64));
        v = __shfl(v,0,64);
        float e0 = expf(sc[tid]-v), e1 = expf(sc[tid+64]-v);
        float se = e0+e1;
        #pragma unroll
        for (int o=32;o>0;o>>=1) se += __shfl_down(se,o,64);
        se = __shfl(se,0,64);
        float inv = wss_s/se;
        sc[tid]    = e0*inv;
        sc[tid+64] = e1*inv;
    }
    __syncthreads();

    // D: memory update
    for (int i = tid; i < N_*D_; i += 256){
        int n = i>>6, d = i&63;
        float ww = sc[n];
        mrow0[i] = mrow0[i]*(1.f - ww*ers[d]) + ww*ads[d];
    }
    __syncthreads();

    // E: post-write stats, read scores, per-r softmax
    if (tid < N_){
        const float* row = mrow0 + tid*D_;
        float ss=0,qq=0;
        for (int d=0;d<D_;d+=4){
            float4 u = *(const float4*)(row+d);
            ss += u.x+u.y+u.z+u.w;
            qq += u.x*u.x+u.y*u.y+u.z*u.z+u.w*u.w;
        }
        float mr = ss*(1.f/D_);
        mst[0][tid] = mr;
        mst[1][tid] = rsqrtf(qq*(1.f/D_)-mr*mr+1e-5f);
    }
    __syncthreads();
    {
        int r0 = tid>>7, n = tid&127;
        const float* row = mrow0 + n*D_;
        float mr = mst[0][n], rr = mst[1][n];
        float a0=0,a1=0;
        for (int d=0;d<D_;d++){
            float nm = (row[d]-mr)*rr*g_mem[d]+b_ln_mem[d];
            a0 += rks[r0][d]*nm;
            a1 += rks[r0+2][d]*nm;
        }
        s2s[r0][n]=a0; s2s[r0+2][n]=a1;
    }
    __syncthreads();
    {
        int r = tid>>6, lane = tid&63;
        float v = fmaxf(s2s[r][lane], s2s[r][lane+64]);
        #pragma unroll
        for (int o=32;o>0;o>>=1) v = fmaxf(v, __shfl_down(v,o,64));
        v = __shfl(v,0,64);
        float e0 = expf(s2s[r][lane]-v), e1 = expf(s2s[r][lane+64]-v);
        float se = e0+e1;
        #pragma unroll
        for (int o=32;o>0;o>>=1) se += __shfl_down(se,o,64);
        se = __shfl(se,0,64);
        float inv = 1.f/se;
        s2s[r][lane]    = e0*inv;
        s2s[r][lane+64] = e1*inv;
    }
    __syncthreads();

    // F: rvec
    {
        int r = tid>>6, d = tid&63;
        float acc=0;
        for (int n=0;n<N_;n++) acc += s2s[r][n]*mrow0[n*D_+d];
        rvs[tid] = acc;
    }
    __syncthreads();

    // G: po = LN(hn || rv) -> bf16
    {
        float u0=hn_s[tid], u1=hn_s[tid+256], u2=rvs[tid];
        float ssum=u0+u1+u2, sq=u0*u0+u1*u1+u2*u2;
        block_sum2(ssum,sq,scr,tid);
        float mo = ssum*(1.f/TO_);
        float ro = rsqrtf(sq*(1.f/TO_)-mo*mo+1e-5f);
        unsigned short* pb = po_bf + (size_t)b*TO_;
        pb[tid]     = f2bf((u0-mo)*ro*g_out[tid]    +b_out[tid]);
        pb[tid+256] = f2bf((u1-mo)*ro*g_out[tid+256]+b_out[tid+256]);
        pb[tid+512] = f2bf((u2-mo)*ro*g_out[tid+512]+b_out[tid+512]);
    }
    // H: ci_{t+1} = LN(x_{t+1} || rv) -> bf16 into next act buffer
    if (t < L_-1){
        const float* xr = x_emb + ((size_t)b*L_ + t + 1)*E_;
        float u0=xr[tid], u1=xr[tid+256], u2=rvs[tid];
        float ssum=u0+u1+u2, sq=u0*u0+u1*u1+u2*u2;
        block_sum2(ssum,sq,scr,tid);
        float mo = ssum*(1.f/CI_);
        float ro = rsqrtf(sq*(1.f/CI_)-mo*mo+1e-5f);
        unsigned short* cb = act_nxt + (size_t)b*KG_;
        cb[tid]     = f2bf((u0-mo)*ro*g_in[tid]    +b_in[tid]);
        cb[tid+256] = f2bf((u1-mo)*ro*g_in[tid+256]+b_in[tid+256]);
        cb[tid+512] = f2bf((u2-mo)*ro*g_in[tid+512]+b_in[tid+512]);
    }
    __syncthreads();
    if (tid == 0){ hsum[b] = 0.f; hsum[64+b] = 0.f; }
}

// ci_0 = LN(x_0 || 0) -> bf16 into act0
__global__ __launch_bounds__(256,1) void ci0_kernel(
    const float* __restrict__ x_emb,
    const float* __restrict__ g_in, const float* __restrict__ b_in,
    unsigned short* __restrict__ act0)
{
    int b = blockIdx.x, tid = threadIdx.x;
    __shared__ float scr[8];
    const float* xr = x_emb + (size_t)b*L_*E_;
    float u0=xr[tid], u1=xr[tid+256], u2=0.f;
    float s=u0+u1+u2, q=u0*u0+u1*u1+u2*u2;
    block_sum2(s,q,scr,tid);
    float m  = s*(1.f/CI_);
    float rs = rsqrtf(q*(1.f/CI_)-m*m+1e-5f);
    unsigned short* cb = act0 + (size_t)b*KG_;
    cb[tid]     = f2bf((u0-m)*rs*g_in[tid]    +b_in[tid]);
    cb[tid+256] = f2bf((u1-m)*rs*g_in[tid+256]+b_in[tid+256]);
    cb[tid+512] = f2bf((u2-m)*rs*g_in[tid+512]+b_in[tid+512]);
}

__global__ void epi_kernel(const float* __restrict__ mem, const float* __restrict__ hfin,
                           const float* __restrict__ cfin, float* __restrict__ out)
{
    size_t i = (size_t)blockIdx.x*256 + threadIdx.x;
    const size_t o0 = (size_t)B_*L_*O_;
    if (i < (size_t)B_*N_*D_) out[o0 + i] = mem[i];
    if (i < (size_t)B_*H_){
        out[o0 + (size_t)B_*N_*D_ + i]                 = hfin[i];
        out[o0 + (size_t)B_*N_*D_ + (size_t)B_*H_ + i] = cfin[i];
    }
}

extern "C" void kernel_launch(void* const* d_in, const int* in_sizes, int n_in,
                              void* d_out, int out_size, void* d_ws, size_t ws_size,
                              hipStream_t stream)
{
    const float* x_emb  = (const float*)d_in[0];
    const float* g_in   = (const float*)d_in[1];
    const float* b_in   = (const float*)d_in[2];
    const float* W_ih   = (const float*)d_in[3];
    const float* W_hh   = (const float*)d_in[4];
    const float* b_ih   = (const float*)d_in[5];
    const float* b_hh   = (const float*)d_in[6];
    const float* g_ctrl = (const float*)d_in[7];
    const float* b_ctrl = (const float*)d_in[8];
    const float* W_rk   = (const float*)d_in[9];
    const float* b_rk   = (const float*)d_in[10];
    const float* W_wk   = (const float*)d_in[11];
    const float* b_wk   = (const float*)d_in[12];
    const float* W_ws   = (const float*)d_in[13];
    const float* b_ws   = (const float*)d_in[14];
    const float* W_er   = (const float*)d_in[15];
    const float* b_er   = (const float*)d_in[16];
    const float* W_ad   = (const float*)d_in[17];
    const float* b_ad   = (const float*)d_in[18];
    const float* g_rk   = (const float*)d_in[19];
    const float* b_ln_rk= (const float*)d_in[20];
    const float* g_wk   = (const float*)d_in[21];
    const float* b_ln_wk= (const float*)d_in[22];
    const float* g_mem  = (const float*)d_in[23];
    const float* b_ln_mem=(const float*)d_in[24];
    const float* g_out  = (const float*)d_in[25];
    const float* b_out  = (const float*)d_in[26];
    const float* W_proj = (const float*)d_in[27];
    const float* b_proj = (const float*)d_in[28];

    char* ws = (char*)d_ws;
    size_t off = 0;
    unsigned short* Wg_bf = (unsigned short*)(ws + off); off += (size_t)2048*KG_*2;   // 5242880
    unsigned short* Wp_bf = (unsigned short*)(ws + off); off += (size_t)2048*KP_*2;   // 3145728
    float*  biasg  = (float*)(ws + off);  off += 2048*4;                              // 8192
    float*  headT  = (float*)(ws + off);  off += (size_t)449*64*4;                    // 114944
    unsigned short* po_bf = (unsigned short*)(ws + off); off += (size_t)B_*TO_*2;     // 98304
    size_t zero_off = off;
    unsigned short* act0 = (unsigned short*)(ws + off); off += (size_t)B_*KG_*2;      // 163840
    unsigned short* act1 = (unsigned short*)(ws + off); off += (size_t)B_*KG_*2;      // 163840
    float* h_nat = (float*)(ws + off); off += (size_t)B_*H_*4;                        // 131072
    float* cst   = (float*)(ws + off); off += (size_t)B_*H_*4;                        // 131072
    float* mem   = (float*)(ws + off); off += (size_t)B_*N_*D_*4;                     // 2097152
    float* hsum  = (float*)(ws + off); off += 128*4;                                  // 512
    size_t zero_sz = off - zero_off;
    float* out = (float*)d_out;

    hipMemsetAsync(ws + zero_off, 0, zero_sz, stream);
    convG_kernel<<<2048*5, 256, 0, stream>>>(W_ih, W_hh, b_ih, b_hh, Wg_bf, biasg);
    convP_kernel<<<2048*3, 256, 0, stream>>>(W_proj, Wp_bf);
    ci0_kernel<<<64, 256, 0, stream>>>(x_emb, g_in, b_in, act0);

    for (int t=0; t<=L_; ++t){
        unsigned short* act_cur = (t&1) ? act1 : act0;
        unsigned short* act_nxt = (t&1) ? act0 : act1;
        k1_mfma<<<32, 256, 0, stream>>>(Wg_bf, Wp_bf, biasg, b_proj,
            act_cur, act_nxt, po_bf, cst, h_nat, hsum, out, t);
        if (t < L_){
            k2h_kernel<<<57, 256, 0, stream>>>(h_nat, hsum,
                W_rk,b_rk, W_wk,b_wk, W_ws,b_ws, W_er,b_er, W_ad,b_ad,
                g_ctrl, b_ctrl, headT);
            k2m_kernel<<<64, 256, 0, stream>>>(h_nat, hsum, headT, mem,
                act_nxt, po_bf, x_emb,
                g_ctrl,b_ctrl, g_rk,b_ln_rk, g_wk,b_ln_wk, g_mem,b_ln_mem,
                g_in,b_in, g_out,b_out, t);
        }
    }
    epi_kernel<<<2048, 256, 0, stream>>>(mem, h_nat, cst, out);
}